// Round 1
// baseline (96.328 us; speedup 1.0000x reference)
//
#include <hip/hip_runtime.h>

#define RBF_GAMMA (1.0f / 128.0f)

__global__ void __launch_bounds__(256) CustomRBF_74234214744185_kernel(
    const float* __restrict__ X,
    const float* __restrict__ centroid,
    const float* __restrict__ w,
    const float* __restrict__ b,
    float* __restrict__ out,
    int N)
{
    const int sub = threadIdx.x & 31;              // lane within 32-lane row-group

    // Preload this lane's centroid chunk (4 floats) once.
    const float4 c = reinterpret_cast<const float4*>(centroid)[sub];
    const float w0 = w[0];
    const float b0 = b[0];

    int group = (int)((blockIdx.x * blockDim.x + threadIdx.x) >> 5);
    const int ngroups = (int)((gridDim.x * blockDim.x) >> 5);

    for (int r = group; r < N; r += ngroups) {
        // Row r is 128 f32 = 512 B contiguous; 32 lanes x float4 covers it.
        const float4 x = reinterpret_cast<const float4*>(X + (size_t)r * 128)[sub];
        const float d0 = x.x - c.x;
        const float d1 = x.y - c.y;
        const float d2 = x.z - c.z;
        const float d3 = x.w - c.w;
        float s = d0 * d0 + d1 * d1 + d2 * d2 + d3 * d3;

        // Reduce across the 32-lane group (xor masks < 32 stay in-group).
        s += __shfl_xor(s, 16);
        s += __shfl_xor(s, 8);
        s += __shfl_xor(s, 4);
        s += __shfl_xor(s, 2);
        s += __shfl_xor(s, 1);

        if (sub == 0) {
            out[r] = __expf(-RBF_GAMMA * s) * w0 + b0;
        }
    }
}

extern "C" void kernel_launch(void* const* d_in, const int* in_sizes, int n_in,
                              void* d_out, int out_size, void* d_ws, size_t ws_size,
                              hipStream_t stream) {
    const float* X        = (const float*)d_in[0];
    const float* centroid = (const float*)d_in[1];
    const float* w        = (const float*)d_in[2];
    const float* b        = (const float*)d_in[3];
    float* out            = (float*)d_out;

    const int N = out_size;  // 1,000,000 rows

    const int block = 256;
    const int grid  = 2048;  // grid-stride; 16384 row-groups
    CustomRBF_74234214744185_kernel<<<grid, block, 0, stream>>>(
        X, centroid, w, b, out, N);
}

// Round 3
// 96.021 us; speedup vs baseline: 1.0032x; 1.0032x over previous
//
#include <hip/hip_runtime.h>

#define RBF_GAMMA (1.0f / 128.0f)

typedef float f32x4 __attribute__((ext_vector_type(4)));

__global__ void __launch_bounds__(256) CustomRBF_74234214744185_kernel(
    const float* __restrict__ X,
    const float* __restrict__ centroid,
    const float* __restrict__ w,
    const float* __restrict__ b,
    float* __restrict__ out,
    int N)
{
    const int sub = threadIdx.x & 31;              // lane within 32-lane row-group

    // Preload this lane's centroid chunk (4 floats) once.
    const f32x4 c = reinterpret_cast<const f32x4*>(centroid)[sub];
    const float w0 = w[0];
    const float b0 = b[0];

    const int group0  = (int)((blockIdx.x * blockDim.x + threadIdx.x) >> 5);
    const int ngroups = (int)((gridDim.x * blockDim.x) >> 5);

    // Per-lane base pointer: lane sub covers float4 #sub of each 32-float4 row.
    const f32x4* __restrict__ Xv = reinterpret_cast<const f32x4*>(X) + sub;

    int r = group0;

    // Unrolled x2: two independent nontemporal loads in flight per wave.
    for (; r + ngroups < N; r += 2 * ngroups) {
        const f32x4 x0 = __builtin_nontemporal_load(Xv + (long long)r * 32);
        const f32x4 x1 = __builtin_nontemporal_load(Xv + (long long)(r + ngroups) * 32);

        const f32x4 d0 = x0 - c;
        const f32x4 d1 = x1 - c;

        float s0 = d0.x * d0.x + d0.y * d0.y + d0.z * d0.z + d0.w * d0.w;
        float s1 = d1.x * d1.x + d1.y * d1.y + d1.z * d1.z + d1.w * d1.w;

        s0 += __shfl_xor(s0, 16);  s1 += __shfl_xor(s1, 16);
        s0 += __shfl_xor(s0, 8);   s1 += __shfl_xor(s1, 8);
        s0 += __shfl_xor(s0, 4);   s1 += __shfl_xor(s1, 4);
        s0 += __shfl_xor(s0, 2);   s1 += __shfl_xor(s1, 2);
        s0 += __shfl_xor(s0, 1);   s1 += __shfl_xor(s1, 1);

        if (sub == 0) {
            out[r]           = __expf(-RBF_GAMMA * s0) * w0 + b0;
            out[r + ngroups] = __expf(-RBF_GAMMA * s1) * w0 + b0;
        }
    }

    // Tail: at most one leftover row per group.
    if (r < N) {
        const f32x4 x = __builtin_nontemporal_load(Xv + (long long)r * 32);
        const f32x4 d = x - c;
        float s = d.x * d.x + d.y * d.y + d.z * d.z + d.w * d.w;
        s += __shfl_xor(s, 16);
        s += __shfl_xor(s, 8);
        s += __shfl_xor(s, 4);
        s += __shfl_xor(s, 2);
        s += __shfl_xor(s, 1);
        if (sub == 0) {
            out[r] = __expf(-RBF_GAMMA * s) * w0 + b0;
        }
    }
}

extern "C" void kernel_launch(void* const* d_in, const int* in_sizes, int n_in,
                              void* d_out, int out_size, void* d_ws, size_t ws_size,
                              hipStream_t stream) {
    const float* X        = (const float*)d_in[0];
    const float* centroid = (const float*)d_in[1];
    const float* w        = (const float*)d_in[2];
    const float* b        = (const float*)d_in[3];
    float* out            = (float*)d_out;

    const int N = out_size;  // 1,000,000 rows

    const int block = 256;
    const int grid  = 2048;  // 16384 row-groups, ~61 rows each
    CustomRBF_74234214744185_kernel<<<grid, block, 0, stream>>>(
        X, centroid, w, b, out, N);
}

// Round 4
// 95.947 us; speedup vs baseline: 1.0040x; 1.0008x over previous
//
#include <hip/hip_runtime.h>

#define RBF_GAMMA (1.0f / 128.0f)

typedef float f32x4 __attribute__((ext_vector_type(4)));

// DPP-based 32-lane sum reduce: 5 VALU adds, no LDS/DS ops.
// After this, lane 31 holds sum(lanes 0..31) and lane 63 holds sum(lanes 32..63).
__device__ __forceinline__ float dpp_sum32(float s) {
    int v = __builtin_bit_cast(int, s);
    // inclusive-scan shifts within each 16-lane row (bound_ctrl=1: OOB -> 0)
    v = __builtin_bit_cast(int,
        __builtin_bit_cast(float, v) +
        __builtin_bit_cast(float, __builtin_amdgcn_update_dpp(0, v, 0x111, 0xF, 0xF, true))); // row_shr:1
    v = __builtin_bit_cast(int,
        __builtin_bit_cast(float, v) +
        __builtin_bit_cast(float, __builtin_amdgcn_update_dpp(0, v, 0x112, 0xF, 0xF, true))); // row_shr:2
    v = __builtin_bit_cast(int,
        __builtin_bit_cast(float, v) +
        __builtin_bit_cast(float, __builtin_amdgcn_update_dpp(0, v, 0x114, 0xF, 0xF, true))); // row_shr:4
    v = __builtin_bit_cast(int,
        __builtin_bit_cast(float, v) +
        __builtin_bit_cast(float, __builtin_amdgcn_update_dpp(0, v, 0x118, 0xF, 0xF, true))); // row_shr:8
    // lane15 -> lanes 16..31 (and lane47 -> lanes 48..63)
    v = __builtin_bit_cast(int,
        __builtin_bit_cast(float, v) +
        __builtin_bit_cast(float, __builtin_amdgcn_update_dpp(0, v, 0x142, 0xF, 0xF, true))); // row_bcast15
    return __builtin_bit_cast(float, v);
}

__global__ void __launch_bounds__(256) CustomRBF_74234214744185_kernel(
    const float* __restrict__ X,
    const float* __restrict__ centroid,
    const float* __restrict__ w,
    const float* __restrict__ b,
    float* __restrict__ out,
    int N)
{
    const int sub = threadIdx.x & 31;              // lane within 32-lane row-group

    // Preload this lane's centroid chunk (4 floats) once.
    const f32x4 c = reinterpret_cast<const f32x4*>(centroid)[sub];
    const float w0 = w[0];
    const float b0 = b[0];

    const int group0  = (int)((blockIdx.x * blockDim.x + threadIdx.x) >> 5);
    const int ngroups = (int)((gridDim.x * blockDim.x) >> 5);

    // Per-lane base pointer: lane sub covers float4 #sub of each 32-float4 row.
    const f32x4* __restrict__ Xv = reinterpret_cast<const f32x4*>(X) + sub;

    int r = group0;

    // Unrolled x2: two independent nontemporal loads in flight per wave.
    for (; r + ngroups < N; r += 2 * ngroups) {
        const f32x4 x0 = __builtin_nontemporal_load(Xv + (long long)r * 32);
        const f32x4 x1 = __builtin_nontemporal_load(Xv + (long long)(r + ngroups) * 32);

        const f32x4 d0 = x0 - c;
        const f32x4 d1 = x1 - c;

        float s0 = d0.x * d0.x + d0.y * d0.y + d0.z * d0.z + d0.w * d0.w;
        float s1 = d1.x * d1.x + d1.y * d1.y + d1.z * d1.z + d1.w * d1.w;

        s0 = dpp_sum32(s0);
        s1 = dpp_sum32(s1);

        if (sub == 31) {   // lane 31 of each 16-lane row-pair holds the group sum
            out[r]           = __expf(-RBF_GAMMA * s0) * w0 + b0;
            out[r + ngroups] = __expf(-RBF_GAMMA * s1) * w0 + b0;
        }
    }

    // Tail: at most one leftover row per group.
    if (r < N) {
        const f32x4 x = __builtin_nontemporal_load(Xv + (long long)r * 32);
        const f32x4 d = x - c;
        float s = d.x * d.x + d.y * d.y + d.z * d.z + d.w * d.w;
        s = dpp_sum32(s);
        if (sub == 31) {
            out[r] = __expf(-RBF_GAMMA * s) * w0 + b0;
        }
    }
}

extern "C" void kernel_launch(void* const* d_in, const int* in_sizes, int n_in,
                              void* d_out, int out_size, void* d_ws, size_t ws_size,
                              hipStream_t stream) {
    const float* X        = (const float*)d_in[0];
    const float* centroid = (const float*)d_in[1];
    const float* w        = (const float*)d_in[2];
    const float* b        = (const float*)d_in[3];
    float* out            = (float*)d_out;

    const int N = out_size;  // 1,000,000 rows

    const int block = 256;
    const int grid  = 2048;  // 16384 row-groups, ~61 rows each
    CustomRBF_74234214744185_kernel<<<grid, block, 0, stream>>>(
        X, centroid, w, b, out, N);
}